// Round 5
// baseline (1133.609 us; speedup 1.0000x reference)
//
#include <hip/hip_runtime.h>
#include <hip/hip_bf16.h>
#include <cstdint>
#include <cstddef>

// ---------------------------------------------------------------------------
// BsPINN forward. DTYPE MODEL (round-5): inputs fp32, OUTPUT fp32
// (reference returns float32; round-4's 9.03e-2 == bf16-pairs-read-as-fp32
// decorrelation signature, 2*max|ref|). Internal math fp32 + bf16 MFMA.
//   h0 = tanh(norm(X) @ W0 + b0)           K=2        (fp32 vector math)
//   h1 = tanh(h0 @ W1 + b1)                dense 1024 (MFMA)
//   h2 = tanh(h1 @ (W2*mask2) + b2)        2 x 512 block-diag (MFMA, K=512)
//   h3 = tanh(h2 @ (W3*mask3) + b3)        4 x 256 block-diag (MFMA, K=256)
//   out = h3 @ W_last + b_last             (wave dot, fp32 out)
// Precision: activations AND weights carried as hi+lo bf16 pairs; per product
// AhiWhi + AloWhi + AhiWlo (3 MFMAs); dropped AloWlo ~2^-18 rel.
// Row-chunked so ws is never overrun. Explicit ds_write staging (proven).
// ---------------------------------------------------------------------------

typedef __bf16    bf16x8  __attribute__((ext_vector_type(8)));
typedef float     floatx4 __attribute__((ext_vector_type(4)));
typedef float     floatx8 __attribute__((ext_vector_type(8)));
typedef uint16_t  u16x8   __attribute__((ext_vector_type(8)));

__device__ __forceinline__ float bf2f(uint16_t u) {
    union { uint32_t i; float f; } v; v.i = ((uint32_t)u) << 16; return v.f;
}
__device__ __forceinline__ uint16_t f2bf(float f) {
    union { float f; uint32_t i; } v; v.f = f;
    uint32_t x = v.i;
    return (uint16_t)((x + 0x7FFFu + ((x >> 16) & 1u)) >> 16);  // RNE
}
// tanh(x) = 1 - 2/(e^{2x}+1); maps +-inf to +-1, cannot create NaN.
__device__ __forceinline__ float tanh_fast(float x) {
    float e = __expf(2.0f * x);
    return 1.0f - 2.0f / (e + 1.0f);
}

// ---------------------------------------------------------------------------
// Weight transpose + hi/lo split: fp32 W[K=1024][N=1024] -> bf16 Whi/Wlo[N][K].
// ---------------------------------------------------------------------------
__global__ __launch_bounds__(256)
void transposeHL(const float* __restrict__ W,
                 uint16_t* __restrict__ Whi, uint16_t* __restrict__ Wlo) {
    __shared__ float tile[32][33];
    const int tx = threadIdx.x & 31;
    const int ty = threadIdx.x >> 5;     // 0..7
    #pragma unroll
    for (int j = 0; j < 4; ++j) {
        int r = ty + j * 8;
        tile[r][tx] = W[(size_t)(blockIdx.y * 32 + r) * 1024 + blockIdx.x * 32 + tx];
    }
    __syncthreads();
    #pragma unroll
    for (int j = 0; j < 4; ++j) {
        int r = ty + j * 8;
        float v = tile[tx][r];
        uint16_t hi = f2bf(v);
        uint16_t lo = f2bf(v - bf2f(hi));
        const size_t o = (size_t)(blockIdx.x * 32 + r) * 1024 + blockIdx.y * 32 + tx;
        Whi[o] = hi;
        Wlo[o] = lo;
    }
}

// ---------------------------------------------------------------------------
// Layer 0 (fp32 in): h0 = tanh(xa*W0[0][:] + xb*W0[1][:] + b0), hi/lo out.
// xa = x0/pi - 1, xb = 2*x1 - 1. One thread = 8 output cols of one row.
// ---------------------------------------------------------------------------
__global__ __launch_bounds__(256)
void layer0_kernel(const float* __restrict__ X, const float* __restrict__ W0,
                   const float* __restrict__ b0,
                   uint16_t* __restrict__ Hhi, uint16_t* __restrict__ Hlo) {
    const int idx = blockIdx.x * 256 + threadIdx.x;
    const int row = idx >> 7;
    const int j0  = (idx & 127) << 3;
    const float x0 = X[row * 2 + 0];
    const float x1 = X[row * 2 + 1];
    const float xa = x0 * 0.31830988618379067f - 1.0f;   // x0/pi - 1
    const float xb = 2.0f * x1 - 1.0f;
    floatx8 wa = *(const floatx8*)(W0 + j0);
    floatx8 wb = *(const floatx8*)(W0 + 1024 + j0);
    floatx8 bb = *(const floatx8*)(b0 + j0);
    u16x8 oh, ol;
    #pragma unroll
    for (int j = 0; j < 8; ++j) {
        float v = fmaf(xa, wa[j], fmaf(xb, wb[j], bb[j]));
        float o = tanh_fast(v);
        uint16_t hi = f2bf(o);
        oh[j] = hi;
        ol[j] = f2bf(o - bf2f(hi));
    }
    const size_t off = (size_t)row * 1024 + j0;
    *(u16x8*)(Hhi + off) = oh;
    *(u16x8*)(Hlo + off) = ol;
}

// ---------------------------------------------------------------------------
// GEMM + bias + tanh, hi/lo x hi/lo. C = tanh((Ah+Al)@(Wh+Wl) + bias).
// Wt hi/lo are [N][K] row-major. KB = diag block (1024/512/256): output cols
// [n0,n0+128) only need k in [(n0/KB)*KB, +KB).
// 128x128 tile, BK=32, 4 waves (2x2), 4x4 16x16x32 frags, 3 MFMA per frag.
// ---------------------------------------------------------------------------
__global__ __launch_bounds__(256)
void gemm_tanh(const uint16_t* __restrict__ Ahi, const uint16_t* __restrict__ Alo,
               const uint16_t* __restrict__ Wth, const uint16_t* __restrict__ Wtl,
               const float* __restrict__ bias,
               uint16_t* __restrict__ Chi, uint16_t* __restrict__ Clo, int KB) {
    __shared__ uint16_t AsH[128 * 32];
    __shared__ uint16_t AsL[128 * 32];
    __shared__ uint16_t BsH[128 * 32];
    __shared__ uint16_t BsL[128 * 32];

    const int tid  = threadIdx.x;
    const int lane = tid & 63;
    const int wave = tid >> 6;
    const int m0 = blockIdx.x * 128;
    const int n0 = blockIdx.y * 128;
    const int kbeg   = (n0 / KB) * KB;
    const int kiters = KB >> 5;
    const int wm = (wave & 1) << 6;
    const int wn = (wave >> 1) << 6;
    const int r = lane & 15;
    const int q = lane >> 4;

    floatx4 acc[4][4];
    #pragma unroll
    for (int i = 0; i < 4; ++i)
        #pragma unroll
        for (int j = 0; j < 4; ++j)
            acc[i][j] = floatx4{0.f, 0.f, 0.f, 0.f};

    for (int t = 0; t < kiters; ++t) {
        const int k = kbeg + (t << 5);
        u16x8 vah[2], val[2], vbh[2], vbl[2];
        #pragma unroll
        for (int j = 0; j < 2; ++j) {
            const int i   = (j << 8) + tid;       // slot id 0..511
            const int row = i >> 2;               // tile row 0..127
            const int seg = (i & 3) << 3;         // 8-elem segment
            const size_t ga = (size_t)(m0 + row) * 1024 + k + seg;
            const size_t gb = (size_t)(n0 + row) * 1024 + k + seg;
            vah[j] = *(const u16x8*)(Ahi + ga);
            val[j] = *(const u16x8*)(Alo + ga);
            vbh[j] = *(const u16x8*)(Wth + gb);
            vbl[j] = *(const u16x8*)(Wtl + gb);
        }
        __syncthreads();   // prior iteration's ds_reads complete
        #pragma unroll
        for (int j = 0; j < 2; ++j) {
            const int i = (j << 8) + tid;
            *(u16x8*)(AsH + i * 8) = vah[j];
            *(u16x8*)(AsL + i * 8) = val[j];
            *(u16x8*)(BsH + i * 8) = vbh[j];
            *(u16x8*)(BsL + i * 8) = vbl[j];
        }
        __syncthreads();

        bf16x8 ah[4], al[4], bh[4], bl[4];
        #pragma unroll
        for (int i = 0; i < 4; ++i) {
            ah[i] = *(const bf16x8*)(AsH + (wm + i * 16 + r) * 32 + q * 8);
            al[i] = *(const bf16x8*)(AsL + (wm + i * 16 + r) * 32 + q * 8);
            bh[i] = *(const bf16x8*)(BsH + (wn + i * 16 + r) * 32 + q * 8);
            bl[i] = *(const bf16x8*)(BsL + (wn + i * 16 + r) * 32 + q * 8);
        }
        #pragma unroll
        for (int i = 0; i < 4; ++i)
            #pragma unroll
            for (int j = 0; j < 4; ++j) {
                acc[i][j] = __builtin_amdgcn_mfma_f32_16x16x32_bf16(ah[i], bh[j], acc[i][j], 0, 0, 0);
                acc[i][j] = __builtin_amdgcn_mfma_f32_16x16x32_bf16(al[i], bh[j], acc[i][j], 0, 0, 0);
                acc[i][j] = __builtin_amdgcn_mfma_f32_16x16x32_bf16(ah[i], bl[j], acc[i][j], 0, 0, 0);
            }
    }

    // Epilogue. C/D layout: col = lane&15, row = (lane>>4)*4 + reg.
    #pragma unroll
    for (int j = 0; j < 4; ++j) {
        const int col = n0 + wn + j * 16 + r;
        const float bv = bias[col];
        #pragma unroll
        for (int i = 0; i < 4; ++i) {
            const int row0 = m0 + wm + i * 16 + q * 4;
            #pragma unroll
            for (int rr = 0; rr < 4; ++rr) {
                float o = tanh_fast(acc[i][j][rr] + bv);
                const size_t idx = (size_t)(row0 + rr) * 1024 + col;
                uint16_t hi = f2bf(o);
                Chi[idx] = hi;
                Clo[idx] = f2bf(o - bf2f(hi));
            }
        }
    }
}

// ---------------------------------------------------------------------------
// Final: out[row] = (h3hi+h3lo)[row,:] . W_last + b_last. One wave per row.
// W_last fp32; out fp32 (reference output dtype).
// ---------------------------------------------------------------------------
__global__ __launch_bounds__(256)
void final_kernel(const uint16_t* __restrict__ Hhi, const uint16_t* __restrict__ Hlo,
                  const float* __restrict__ Wl, const float* __restrict__ bl,
                  float* __restrict__ out) {
    const int lane = threadIdx.x & 63;
    const int wave = threadIdx.x >> 6;
    const int row  = blockIdx.x * 4 + wave;
    const size_t base = (size_t)row * 1024;
    float s = 0.0f;
    #pragma unroll
    for (int c = 0; c < 2; ++c) {
        const int e = c * 512 + lane * 8;
        u16x8 hv = *(const u16x8*)(Hhi + base + e);
        u16x8 lv = *(const u16x8*)(Hlo + base + e);
        floatx8 wv = *(const floatx8*)(Wl + e);
        #pragma unroll
        for (int j = 0; j < 8; ++j)
            s = fmaf(bf2f(hv[j]) + bf2f(lv[j]), wv[j], s);
    }
    #pragma unroll
    for (int off = 32; off > 0; off >>= 1) s += __shfl_down(s, off);
    if (lane == 0) out[row] = s + bl[0];
}

// ---------------------------------------------------------------------------
extern "C" void kernel_launch(void* const* d_in, const int* in_sizes, int n_in,
                              void* d_out, int out_size, void* d_ws, size_t ws_size,
                              hipStream_t stream) {
    const float* X  = (const float*)d_in[0];
    const float* W0 = (const float*)d_in[1];
    const float* b0 = (const float*)d_in[2];
    const float* W1 = (const float*)d_in[3];
    const float* b1 = (const float*)d_in[4];
    const float* W2 = (const float*)d_in[5];
    const float* b2 = (const float*)d_in[6];
    const float* W3 = (const float*)d_in[7];
    const float* b3 = (const float*)d_in[8];
    const float* Wl = (const float*)d_in[9];
    const float* bl = (const float*)d_in[10];
    float* out = (float*)d_out;

    const int Nrows = in_sizes[0] / 2;                        // 65536
    const size_t WT = 1024 * 1024;                            // elems per Wt plane
    const size_t wt_bytes = 6 * WT * 2;                       // 12 MiB (3 x hi/lo)
    const size_t slack = 512;

    // chunk rows R (pow2): 4 activation planes (Ahi,Alo,Bhi,Blo) must fit ws.
    int R = 0;
    const int Rcap = Nrows < 16384 ? Nrows : 16384;
    for (int r = Rcap; r >= 128; r >>= 1)
        if ((size_t)4 * r * 2048 + wt_bytes + slack <= ws_size) { R = r; break; }
    if (!R) return;  // ws too small — fails visibly

    // ws layout: [Wt1h|Wt1l|Wt2h|Wt2l|Wt3h|Wt3l| P0h|P0l|P1h|P1l]
    uint16_t* wsp  = (uint16_t*)d_ws;
    uint16_t* Wt1h = wsp;           uint16_t* Wt1l = Wt1h + WT;
    uint16_t* Wt2h = Wt1l + WT;     uint16_t* Wt2l = Wt2h + WT;
    uint16_t* Wt3h = Wt2l + WT;     uint16_t* Wt3l = Wt3h + WT;
    const size_t plane = (size_t)R * 1024;
    uint16_t* P0h = Wt3l + WT;      uint16_t* P0l = P0h + plane;
    uint16_t* P1h = P0l + plane;    uint16_t* P1l = P1h + plane;

    const dim3 tb(256);
    transposeHL<<<dim3(32, 32), tb, 0, stream>>>(W1, Wt1h, Wt1l);
    transposeHL<<<dim3(32, 32), tb, 0, stream>>>(W2, Wt2h, Wt2l);
    transposeHL<<<dim3(32, 32), tb, 0, stream>>>(W3, Wt3h, Wt3l);

    const int nchunks = Nrows / R;
    for (int c = 0; c < nchunks; ++c) {
        const float* Xc = X + (size_t)c * R * 2;
        float* outc = out + (size_t)c * R;

        layer0_kernel<<<R / 2, tb, 0, stream>>>(Xc, W0, b0, P0h, P0l);

        const dim3 gg(R / 128, 8);
        gemm_tanh<<<gg, tb, 0, stream>>>(P0h, P0l, Wt1h, Wt1l, b1, P1h, P1l, 1024);
        gemm_tanh<<<gg, tb, 0, stream>>>(P1h, P1l, Wt2h, Wt2l, b2, P0h, P0l, 512);
        gemm_tanh<<<gg, tb, 0, stream>>>(P0h, P0l, Wt3h, Wt3l, b3, P1h, P1l, 256);

        final_kernel<<<R / 4, tb, 0, stream>>>(P1h, P1l, Wl, bl, outc);
    }
}

// Round 6
// 1019.381 us; speedup vs baseline: 1.1121x; 1.1121x over previous
//
#include <hip/hip_runtime.h>
#include <cstdint>
#include <cstddef>

// ---------------------------------------------------------------------------
// BsPINN forward, int8 dual-fixed-point MFMA scheme (round 6).
// Dtypes proven R5: inputs fp32, output fp32.
//   h0 = tanh(norm(X) @ W0 + b0)        K=2   fp32 vector
//   h1 = tanh(h0 @ W1 + b1)             K=1024 MFMA-i8
//   h2 = tanh(h1 @ (W2*m2) + b2)        2 x 512 block-diag (K=512)
//   h3 = tanh(h2 @ (W3*m3) + b3)        4 x 256 block-diag (K=256)
//   out = h3 @ W_last + b_last          fp32 wave dot
// Precision: h = H1*2^-6 + H2*2^-13 (int8 pair, err<=2^-14);
//            w = W1*2^-10 + W2*2^-17 (int8 pair, err<=2^-18, |w|<=0.0542).
// preact = (sum H1W1)*2^-16 + (sum H1W2 + H2W1)*2^-23 + bias; cross terms
// share scale 2^-23 -> ONE extra accumulator. 3 MFMAs per K=64 vs R5's
// 3 per K=32: half the MFMA instructions, half the staging bytes.
// i32 accumulation exact: |accM|<=1024*64*56=3.7M, |accX|<=7.9M << 2^31.
// Dropped H2W2 ~4e-5 rms. Integer MFMA: no NaN paths anywhere.
// ---------------------------------------------------------------------------

typedef int          intx4   __attribute__((ext_vector_type(4)));
typedef float        floatx8 __attribute__((ext_vector_type(8)));
typedef signed char  i8x8    __attribute__((ext_vector_type(8)));

// tanh(x) = 1 - 2/(e^{2x}+1); maps +-inf to +-1, no NaN for finite x.
__device__ __forceinline__ float tanh_fast(float x) {
    float e = __expf(2.0f * x);
    return 1.0f - 2.0f / (e + 1.0f);
}
// h in (-1,1) -> H1 = rne(h*64), H2 = rne((h-H1/64)*8192); both in [-64,64].
__device__ __forceinline__ void quant_h(float o, signed char& q1, signed char& q2) {
    float a = rintf(o * 64.0f);                // exact: *64 is pow2
    float r = fmaf(a, -0.015625f, o);          // o - a/64, exact
    q1 = (signed char)(int)a;
    q2 = (signed char)(int)rintf(r * 8192.0f);
}
// |w|<=0.0542 -> W1 = rne(w*1024) in [-56,56], W2 = rne((w-W1/1024)*2^17).
__device__ __forceinline__ void quant_w(float v, signed char& q1, signed char& q2) {
    float a = rintf(v * 1024.0f);
    float r = fmaf(a, -0.0009765625f, v);      // v - a/1024, exact
    q1 = (signed char)(int)a;
    q2 = (signed char)(int)rintf(r * 131072.0f);
}

// ---------------------------------------------------------------------------
// Weight transpose + int8 hi/lo quant: fp32 W[K][N] -> int8 W1q/W2q[N][K].
// ---------------------------------------------------------------------------
__global__ __launch_bounds__(256)
void transposeQ(const float* __restrict__ W,
                signed char* __restrict__ W1q, signed char* __restrict__ W2q) {
    __shared__ float tile[32][33];
    const int tx = threadIdx.x & 31;
    const int ty = threadIdx.x >> 5;     // 0..7
    #pragma unroll
    for (int j = 0; j < 4; ++j) {
        int r = ty + j * 8;
        tile[r][tx] = W[(size_t)(blockIdx.y * 32 + r) * 1024 + blockIdx.x * 32 + tx];
    }
    __syncthreads();
    #pragma unroll
    for (int j = 0; j < 4; ++j) {
        int r = ty + j * 8;
        float v = tile[tx][r];
        signed char q1, q2;
        quant_w(v, q1, q2);
        const size_t o = (size_t)(blockIdx.x * 32 + r) * 1024 + blockIdx.y * 32 + tx;
        W1q[o] = q1;
        W2q[o] = q2;
    }
}

// ---------------------------------------------------------------------------
// Layer 0 (fp32 in): h0 = tanh(xa*W0[0][:] + xb*W0[1][:] + b0) -> int8 pair.
// xa = x0/pi - 1, xb = 2*x1 - 1. One thread = 8 output cols of one row.
// ---------------------------------------------------------------------------
__global__ __launch_bounds__(256)
void layer0_kernel(const float* __restrict__ X, const float* __restrict__ W0,
                   const float* __restrict__ b0,
                   signed char* __restrict__ H1, signed char* __restrict__ H2) {
    const int idx = blockIdx.x * 256 + threadIdx.x;
    const int row = idx >> 7;
    const int j0  = (idx & 127) << 3;
    const float x0 = X[row * 2 + 0];
    const float x1 = X[row * 2 + 1];
    const float xa = x0 * 0.31830988618379067f - 1.0f;   // x0/pi - 1
    const float xb = 2.0f * x1 - 1.0f;
    floatx8 wa = *(const floatx8*)(W0 + j0);
    floatx8 wb = *(const floatx8*)(W0 + 1024 + j0);
    floatx8 bb = *(const floatx8*)(b0 + j0);
    i8x8 o1, o2;
    #pragma unroll
    for (int j = 0; j < 8; ++j) {
        float v = fmaf(xa, wa[j], fmaf(xb, wb[j], bb[j]));
        float o = tanh_fast(v);
        signed char q1, q2;
        quant_h(o, q1, q2);
        o1[j] = q1;
        o2[j] = q2;
    }
    const size_t off = (size_t)row * 1024 + j0;
    *(i8x8*)(H1 + off) = o1;
    *(i8x8*)(H2 + off) = o2;
}

// ---------------------------------------------------------------------------
// GEMM + bias + tanh, int8 dual-fixed-point.
// A planes H1/H2 [rows][1024] i8; weights W1q/W2q [N][K] i8.
// KB = diag block (1024/512/256): cols [n0,n0+128) need k in [(n0/KB)*KB,+KB).
// 128x128 tile, BK=64, 4 waves (2x2), 4x4 16x16x64 frags.
// 3 MFMAs/frag/kiter: accM += H1*W1; accX += H2*W1 + H1*W2.
// ---------------------------------------------------------------------------
__global__ __launch_bounds__(256)
void gemm_tanh_i8(const signed char* __restrict__ A1, const signed char* __restrict__ A2,
                  const signed char* __restrict__ B1, const signed char* __restrict__ B2,
                  const float* __restrict__ bias,
                  signed char* __restrict__ C1, signed char* __restrict__ C2, int KB) {
    __shared__ signed char As1[128 * 64];
    __shared__ signed char As2[128 * 64];
    __shared__ signed char Bs1[128 * 64];
    __shared__ signed char Bs2[128 * 64];

    const int tid  = threadIdx.x;
    const int lane = tid & 63;
    const int wave = tid >> 6;
    const int m0 = blockIdx.x * 128;
    const int n0 = blockIdx.y * 128;
    const int kbeg   = (n0 / KB) * KB;
    const int kiters = KB >> 6;
    const int wm = (wave & 1) << 6;
    const int wn = (wave >> 1) << 6;
    const int r = lane & 15;
    const int q = lane >> 4;

    intx4 accM[4][4], accX[4][4];
    #pragma unroll
    for (int i = 0; i < 4; ++i)
        #pragma unroll
        for (int j = 0; j < 4; ++j) {
            accM[i][j] = intx4{0, 0, 0, 0};
            accX[i][j] = intx4{0, 0, 0, 0};
        }

    for (int t = 0; t < kiters; ++t) {
        const int k = kbeg + (t << 6);
        // Stage 4 tiles of 128x64 i8 = 8 KB each; 512 16B slots, 2/thread.
        intx4 va1[2], va2[2], vb1[2], vb2[2];
        #pragma unroll
        for (int j = 0; j < 2; ++j) {
            const int i   = (j << 8) + tid;       // slot 0..511
            const int row = i >> 2;               // tile row 0..127
            const int seg = (i & 3) << 4;         // 16B segment in 64B row
            const size_t ga = (size_t)(m0 + row) * 1024 + k + seg;
            const size_t gb = (size_t)(n0 + row) * 1024 + k + seg;
            va1[j] = *(const intx4*)(A1 + ga);
            va2[j] = *(const intx4*)(A2 + ga);
            vb1[j] = *(const intx4*)(B1 + gb);
            vb2[j] = *(const intx4*)(B2 + gb);
        }
        __syncthreads();   // prior iteration's ds_reads complete
        #pragma unroll
        for (int j = 0; j < 2; ++j) {
            const int i = (j << 8) + tid;
            *(intx4*)(As1 + i * 16) = va1[j];
            *(intx4*)(As2 + i * 16) = va2[j];
            *(intx4*)(Bs1 + i * 16) = vb1[j];
            *(intx4*)(Bs2 + i * 16) = vb2[j];
        }
        __syncthreads();

        intx4 a1[4], b1[4];
        #pragma unroll
        for (int i = 0; i < 4; ++i) {
            a1[i] = *(const intx4*)(As1 + (wm + i * 16 + r) * 64 + q * 16);
            b1[i] = *(const intx4*)(Bs1 + (wn + i * 16 + r) * 64 + q * 16);
        }
        #pragma unroll
        for (int i = 0; i < 4; ++i)
            #pragma unroll
            for (int j = 0; j < 4; ++j)
                accM[i][j] = __builtin_amdgcn_mfma_i32_16x16x64_i8(a1[i], b1[j], accM[i][j], 0, 0, 0);
        intx4 a2[4];
        #pragma unroll
        for (int i = 0; i < 4; ++i)
            a2[i] = *(const intx4*)(As2 + (wm + i * 16 + r) * 64 + q * 16);
        #pragma unroll
        for (int i = 0; i < 4; ++i)
            #pragma unroll
            for (int j = 0; j < 4; ++j)
                accX[i][j] = __builtin_amdgcn_mfma_i32_16x16x64_i8(a2[i], b1[j], accX[i][j], 0, 0, 0);
        intx4 b2[4];
        #pragma unroll
        for (int i = 0; i < 4; ++i)
            b2[i] = *(const intx4*)(Bs2 + (wn + i * 16 + r) * 64 + q * 16);
        #pragma unroll
        for (int i = 0; i < 4; ++i)
            #pragma unroll
            for (int j = 0; j < 4; ++j)
                accX[i][j] = __builtin_amdgcn_mfma_i32_16x16x64_i8(a1[i], b2[j], accX[i][j], 0, 0, 0);
    }

    // Epilogue. C/D layout (verified, dtype-independent): col=lane&15,
    // row=(lane>>4)*4+reg.
    #pragma unroll
    for (int j = 0; j < 4; ++j) {
        const int col = n0 + wn + j * 16 + r;
        const float bv = bias[col];
        #pragma unroll
        for (int i = 0; i < 4; ++i) {
            const int row0 = m0 + wm + i * 16 + q * 4;
            #pragma unroll
            for (int rr = 0; rr < 4; ++rr) {
                float pre = fmaf((float)accM[i][j][rr], 0x1p-16f,
                            fmaf((float)accX[i][j][rr], 0x1p-23f, bv));
                float o = tanh_fast(pre);
                signed char q1, q2;
                quant_h(o, q1, q2);
                const size_t idx = (size_t)(row0 + rr) * 1024 + col;
                C1[idx] = q1;
                C2[idx] = q2;
            }
        }
    }
}

// ---------------------------------------------------------------------------
// Final: out[row] = h3[row,:] . W_last + b_last; h3 = H1*2^-6 + H2*2^-13.
// One wave per row; fp32 out.
// ---------------------------------------------------------------------------
__global__ __launch_bounds__(256)
void final_kernel(const signed char* __restrict__ H1, const signed char* __restrict__ H2,
                  const float* __restrict__ Wl, const float* __restrict__ bl,
                  float* __restrict__ out) {
    const int lane = threadIdx.x & 63;
    const int wave = threadIdx.x >> 6;
    const int row  = blockIdx.x * 4 + wave;
    const size_t base = (size_t)row * 1024;
    float s = 0.0f;
    #pragma unroll
    for (int c = 0; c < 2; ++c) {
        const int e = c * 512 + lane * 8;
        i8x8 h1 = *(const i8x8*)(H1 + base + e);
        i8x8 h2 = *(const i8x8*)(H2 + base + e);
        floatx8 wv = *(const floatx8*)(Wl + e);
        #pragma unroll
        for (int j = 0; j < 8; ++j) {
            float h = fmaf((float)h2[j], 0x1p-13f, (float)h1[j] * 0x1p-6f);
            s = fmaf(h, wv[j], s);
        }
    }
    #pragma unroll
    for (int off = 32; off > 0; off >>= 1) s += __shfl_down(s, off);
    if (lane == 0) out[row] = s + bl[0];
}

// ---------------------------------------------------------------------------
extern "C" void kernel_launch(void* const* d_in, const int* in_sizes, int n_in,
                              void* d_out, int out_size, void* d_ws, size_t ws_size,
                              hipStream_t stream) {
    const float* X  = (const float*)d_in[0];
    const float* W0 = (const float*)d_in[1];
    const float* b0 = (const float*)d_in[2];
    const float* W1 = (const float*)d_in[3];
    const float* b1 = (const float*)d_in[4];
    const float* W2 = (const float*)d_in[5];
    const float* b2 = (const float*)d_in[6];
    const float* W3 = (const float*)d_in[7];
    const float* b3 = (const float*)d_in[8];
    const float* Wl = (const float*)d_in[9];
    const float* bl = (const float*)d_in[10];
    float* out = (float*)d_out;

    const int Nrows = in_sizes[0] / 2;                 // 65536
    const size_t WT = 1024 * 1024;                     // bytes per i8 weight plane
    const size_t wt_bytes = 6 * WT;                    // 6 MiB (3 layers x hi/lo)
    const size_t slack = 512;

    // chunk rows R (pow2): 4 int8 activation planes (R*1024 B each) must fit.
    int R = 0;
    const int Rcap = Nrows < 32768 ? Nrows : 32768;
    for (int r = Rcap; r >= 128; r >>= 1)
        if ((size_t)4 * r * 1024 + wt_bytes + slack <= ws_size) { R = r; break; }
    if (!R) return;

    // ws layout: [W1q1|W1q2|W2q1|W2q2|W3q1|W3q2| P0a|P0b|P1a|P1b]
    signed char* wsp  = (signed char*)d_ws;
    signed char* Wt1a = wsp;            signed char* Wt1b = Wt1a + WT;
    signed char* Wt2a = Wt1b + WT;      signed char* Wt2b = Wt2a + WT;
    signed char* Wt3a = Wt2b + WT;      signed char* Wt3b = Wt3a + WT;
    const size_t plane = (size_t)R * 1024;
    signed char* P0a = Wt3b + WT;       signed char* P0b = P0a + plane;
    signed char* P1a = P0b + plane;     signed char* P1b = P1a + plane;

    const dim3 tb(256);
    transposeQ<<<dim3(32, 32), tb, 0, stream>>>(W1, Wt1a, Wt1b);
    transposeQ<<<dim3(32, 32), tb, 0, stream>>>(W2, Wt2a, Wt2b);
    transposeQ<<<dim3(32, 32), tb, 0, stream>>>(W3, Wt3a, Wt3b);

    const int nchunks = Nrows / R;
    for (int c = 0; c < nchunks; ++c) {
        const float* Xc = X + (size_t)c * R * 2;
        float* outc = out + (size_t)c * R;

        layer0_kernel<<<R / 2, tb, 0, stream>>>(Xc, W0, b0, P0a, P0b);

        const dim3 gg(R / 128, 8);
        gemm_tanh_i8<<<gg, tb, 0, stream>>>(P0a, P0b, Wt1a, Wt1b, b1, P1a, P1b, 1024);
        gemm_tanh_i8<<<gg, tb, 0, stream>>>(P1a, P1b, Wt2a, Wt2b, b2, P0a, P0b, 512);
        gemm_tanh_i8<<<gg, tb, 0, stream>>>(P0a, P0b, Wt3a, Wt3b, b3, P1a, P1b, 256);

        final_kernel<<<R / 4, tb, 0, stream>>>(P1a, P1b, Wl, bl, outc);
    }
}